// Round 16
// baseline (604.590 us; speedup 1.0000x reference)
//
#include <hip/hip_runtime.h>
#include <hip/hip_bf16.h>

// Sizes (fixed): B=64 T=128 HID=512 LOC_EMB=256 TIM_EMB=64 UID_EMB=128
// L_HIST=1024 G=4, K_x=320, K_attn=448, N_gates=1536, UID_SIZE=5000

typedef __attribute__((ext_vector_type(8))) short bf16x8;
typedef __attribute__((ext_vector_type(4))) float f32x4;
typedef __attribute__((ext_vector_type(4))) unsigned short u16x4;
typedef __attribute__((ext_vector_type(2))) unsigned long long u64x2;
typedef unsigned long long u64;

__device__ inline unsigned short f2bf(float x) {
  __hip_bfloat16 b = __float2bfloat16(x);
  return __builtin_bit_cast(unsigned short, b);
}
__device__ inline bf16x8 pack8(float4 a, float4 b) {
  bf16x8 w;
  w[0]=(short)f2bf(a.x); w[1]=(short)f2bf(a.y); w[2]=(short)f2bf(a.z); w[3]=(short)f2bf(a.w);
  w[4]=(short)f2bf(b.x); w[5]=(short)f2bf(b.y); w[6]=(short)f2bf(b.z); w[7]=(short)f2bf(b.w);
  return w;
}

// ============ single megakernel: GRU (0..63) + gx GEMM (64..191) + attn GEMM/fold/ctx (192..255) ============
// sync dwords: [0,1024)    GRU step flags (4 grp x 16 blocks x 16dw)
//              [1024,2048) batchdone[b]   (64 x 16dw; ==16 when lastb[b] final)
//              [2048,3072) gxdone[yt]     (64 x 16dw; ==12 when gx rows [yt*128,+128) ready)
//              [3072]      histt_done     (64 attn blocks)
// gx tiles are written with relaxed L3-direct atomic stores (no L2 writeback needed);
// GRU gates on gxdone[t>>1] with a lane-0-only s_sleep poll (once per 2 steps).
__global__ __launch_bounds__(256)
void gru_attn(const float* __restrict__ W_hh,
              const float* __restrict__ b_hh, const int* __restrict__ lens,
              short* __restrict__ h_bf, float* __restrict__ lastb,
              unsigned int* __restrict__ flags,
              const int* __restrict__ loc, const int* __restrict__ tim,
              const int* __restrict__ hloc, const int* __restrict__ htim,
              const int* __restrict__ huid,
              const float* __restrict__ eloc, const float* __restrict__ etim,
              const float* __restrict__ euid,
              const float* __restrict__ W_ih, const float* __restrict__ b_ih,
              const float* __restrict__ W_attn, const float* __restrict__ b_attn,
              const float* __restrict__ Wf, float* __restrict__ Wfold,
              float* __restrict__ gx, float* __restrict__ histt, float* __restrict__ ctx) {
  __shared__ short smem[6 * 16 * 512];   // 96 KB shared by all roles
  const int bid = blockIdx.x;
  const int tid = threadIdx.x;

  if (bid < 64) {
    // ===================== GRU role =====================
    const int grp0 = bid & 3;
    const int b00 = grp0 << 4;
    int tmax = 0;
    for (int i = 0; i < 16; ++i) tmax = max(tmax, lens[b00 + i]);   // group-uniform

    if (tid >= 128) {                    // idle waves: match barrier count exactly
      for (int t = 0; t < tmax + 1; ++t) __syncthreads();
      return;
    }
    const int lane = tid & 63, tt = tid >> 6;
    const int c = bid >> 2, grp = grp0;
    const int j0 = (c << 5) + (tt << 4);
    const int b0 = b00;
    const int m16 = lane & 15, g4 = lane >> 4;

    for (int gi = 0; gi < 3; ++gi) {
      const float* wg = W_hh + (size_t)(gi * 512 + j0) * 512;
      short* slab = smem + (((gi << 1) + tt) << 13);
      for (int r = 0; r < 16; ++r) {
        int k = lane << 3;
        const float4* src = (const float4*)(wg + (size_t)r * 512 + k);
        int off = ((r << 9) + k) ^ ((r & 7) << 3);
        *(bf16x8*)(slab + off) = pack8(src[0], src[1]);
      }
    }
    __syncthreads();                     // barrier 1

    const int bcol = b0 + m16;
    const int jr = j0 + (g4 << 2);
    const f32x4 bhr = *(const f32x4*)&b_hh[jr];
    const f32x4 bhz = *(const f32x4*)&b_hh[512 + jr];
    const f32x4 bhn = *(const f32x4*)&b_hh[1024 + jr];
    const int lenb = lens[bcol];
    f32x4 hprev = {0.f, 0.f, 0.f, 0.f};

    unsigned int* gflags = flags + (grp << 8);
    unsigned int* ownflag = gflags + (c << 4);
    unsigned int* bdone = flags + 1024;
    unsigned int* gxdone = flags + 2048;

    for (int t = 0; t < tmax; ++t) {
      // gate: gx M-tile (t>>1) produced (lane-0 poll, usually already satisfied)
      if (!(t & 1)) {
        if (lane == 0) {
          while (__hip_atomic_load(gxdone + ((t >> 1) << 4), __ATOMIC_RELAXED,
                                   __HIP_MEMORY_SCOPE_AGENT) < 12u)
            __builtin_amdgcn_s_sleep(1);
        }
        asm volatile("" ::: "memory");
      }
      // gx loads: L3-direct atomics (producers stored L3-direct; fresh by construction)
      const u64* gxp = (const u64*)(gx + ((size_t)t * 64 + bcol) * 1536 + jr);
      u64 g0 = __hip_atomic_load(gxp,       __ATOMIC_RELAXED, __HIP_MEMORY_SCOPE_AGENT);
      u64 g1 = __hip_atomic_load(gxp + 1,   __ATOMIC_RELAXED, __HIP_MEMORY_SCOPE_AGENT);
      u64 g2 = __hip_atomic_load(gxp + 256, __ATOMIC_RELAXED, __HIP_MEMORY_SCOPE_AGENT);
      u64 g3 = __hip_atomic_load(gxp + 257, __ATOMIC_RELAXED, __HIP_MEMORY_SCOPE_AGENT);
      u64 g4v= __hip_atomic_load(gxp + 512, __ATOMIC_RELAXED, __HIP_MEMORY_SCOPE_AGENT);
      u64 g5 = __hip_atomic_load(gxp + 513, __ATOMIC_RELAXED, __HIP_MEMORY_SCOPE_AGENT);
      u64x2 p0; p0[0] = g0; p0[1] = g1;
      u64x2 p1; p1[0] = g2; p1[1] = g3;
      u64x2 p2; p2[0] = g4v; p2[1] = g5;
      f32x4 gr = __builtin_bit_cast(f32x4, p0);
      f32x4 gz = __builtin_bit_cast(f32x4, p1);
      f32x4 gn = __builtin_bit_cast(f32x4, p2);

      f32x4 ar = {0.f, 0.f, 0.f, 0.f}, az = ar, an = ar;
      if (t) {
        unsigned tgt = (unsigned)t;
        while (true) {
          unsigned f = tgt;
          if (lane < 16)
            f = __hip_atomic_load(gflags + (lane << 4), __ATOMIC_RELAXED, __HIP_MEMORY_SCOPE_AGENT);
          if (__all((int)(f >= tgt))) break;
        }
        asm volatile("" ::: "memory");

        const u64* hp = (const u64*)(h_bf + ((t & 1) << 15) + (size_t)bcol * 512 + (g4 << 3));
        u64 hu[32];
#pragma unroll
        for (int ks = 0; ks < 16; ++ks) {
          hu[2 * ks]     = __hip_atomic_load(hp + ks * 8,     __ATOMIC_RELAXED, __HIP_MEMORY_SCOPE_AGENT);
          hu[2 * ks + 1] = __hip_atomic_load(hp + ks * 8 + 1, __ATOMIC_RELAXED, __HIP_MEMORY_SCOPE_AGENT);
        }
#define GRU_MFMA(ks)                                                                 \
        {                                                                            \
          u64x2 p; p[0] = hu[2 * (ks)]; p[1] = hu[2 * (ks) + 1];                     \
          bf16x8 hf = __builtin_bit_cast(bf16x8, p);                                 \
          int off = ((m16 << 9) + ((ks) << 5) + (g4 << 3)) ^ ((m16 & 7) << 3);       \
          ar = __builtin_amdgcn_mfma_f32_16x16x32_bf16(*(const bf16x8*)(smem + ((0 + tt) << 13) + off), hf, ar, 0, 0, 0); \
          az = __builtin_amdgcn_mfma_f32_16x16x32_bf16(*(const bf16x8*)(smem + ((2 + tt) << 13) + off), hf, az, 0, 0, 0); \
          an = __builtin_amdgcn_mfma_f32_16x16x32_bf16(*(const bf16x8*)(smem + ((4 + tt) << 13) + off), hf, an, 0, 0, 0); \
        }
        GRU_MFMA(0)  GRU_MFMA(1)  GRU_MFMA(2)  GRU_MFMA(3)
        GRU_MFMA(4)  GRU_MFMA(5)  GRU_MFMA(6)  GRU_MFMA(7)
        GRU_MFMA(8)  GRU_MFMA(9)  GRU_MFMA(10) GRU_MFMA(11)
        GRU_MFMA(12) GRU_MFMA(13) GRU_MFMA(14) GRU_MFMA(15)
#undef GRU_MFMA
      }
      u16x4 hw;
#pragma unroll
      for (int q = 0; q < 4; ++q) {
        float r = 1.f / (1.f + __expf(-(gr[q] + ar[q] + bhr[q])));
        float z = 1.f / (1.f + __expf(-(gz[q] + az[q] + bhz[q])));
        float xn = gn[q] + r * (an[q] + bhn[q]);
        float n = 1.f - 2.f / (__expf(2.f * xn) + 1.f);
        float hv = (1.f - z) * n + z * hprev[q];
        hprev[q] = hv;
        hw[q] = f2bf(hv);
      }
      __hip_atomic_store((u64*)(h_bf + ((~t & 1) << 15) + (size_t)bcol * 512 + jr),
                         __builtin_bit_cast(u64, hw),
                         __ATOMIC_RELAXED, __HIP_MEMORY_SCOPE_AGENT);
      if (t == lenb - 1) {
        *(f32x4*)(lastb + (size_t)bcol * 512 + jr) = hprev;
      }
      if (t < tmax - 1) {
        asm volatile("s_waitcnt vmcnt(0)" ::: "memory");   // h + lastb stores acked
        __syncthreads();                                   // barriers 2..tmax
        if (tid == 0) {
          __hip_atomic_store(ownflag, (unsigned)(t + 1), __ATOMIC_RELAXED, __HIP_MEMORY_SCOPE_AGENT);
          for (int i = 0; i < 16; ++i)
            if (lens[b0 + i] == t + 1)
              __hip_atomic_fetch_add(bdone + ((b0 + i) << 4), 1u,
                                     __ATOMIC_RELAXED, __HIP_MEMORY_SCOPE_AGENT);
        }
      }
    }
    asm volatile("s_waitcnt vmcnt(0)" ::: "memory");
    __syncthreads();                     // barrier tmax+1
    if (tid == 0) {
      for (int i = 0; i < 16; ++i)
        if (lens[b0 + i] == tmax)
          __hip_atomic_fetch_add(flags + 1024 + ((b0 + i) << 4), 1u,
                                 __ATOMIC_RELAXED, __HIP_MEMORY_SCOPE_AGENT);
    }
    return;
  }

  if (bid < 192) {
    // ===================== gx GEMM role (128 blocks, 768 tiles, yt-major) =====================
    constexpr int LDR = 40, K = 320, N = 1536;
    short* Asl = smem;
    short* Bsl = smem + 128 * LDR;
    const int lane = tid & 63, wid = tid >> 6;
    const int wr = wid >> 1, wc = wid & 1;
    const int m16 = lane & 15, g4 = lane >> 4;
    const int srow = tid >> 1, shalf = tid & 1;
    for (int tile = bid - 64; tile < 768; tile += 128) {
      const int yt = tile / 12, nt = tile % 12;
      const int bm = yt << 7, bn = nt << 7;
      const int grow = bm + srow;
      const int t_ = grow >> 6, b_ = grow & 63;
      const float* aloc = eloc + (size_t)loc[b_ * 128 + t_] * 256 + (shalf << 4);
      const float* atim = etim + (size_t)tim[b_ * 128 + t_] * 64 + (shalf << 4);
      const float* bbase = W_ih + (size_t)(bn + srow) * K + (shalf << 4);
      float4 a0 = ((const float4*)aloc)[0], a1 = ((const float4*)aloc)[1];
      float4 a2 = ((const float4*)aloc)[2], a3 = ((const float4*)aloc)[3];
      float4 w0 = ((const float4*)bbase)[0], w1 = ((const float4*)bbase)[1];
      float4 w2 = ((const float4*)bbase)[2], w3 = ((const float4*)bbase)[3];
      f32x4 acc[4][4] = {};
      for (int k0 = 0; k0 < K; k0 += 32) {
        short* arow = Asl + srow * LDR + (shalf << 4);
        *(bf16x8*)(arow)     = pack8(a0, a1);
        *(bf16x8*)(arow + 8) = pack8(a2, a3);
        short* brow = Bsl + srow * LDR + (shalf << 4);
        *(bf16x8*)(brow)     = pack8(w0, w1);
        *(bf16x8*)(brow + 8) = pack8(w2, w3);
        __syncthreads();
        if (k0 + 32 < K) {              // prefetch next K-tile during MFMA phase
          const int kn = k0 + 32;
          const float* ap = (kn < 256) ? (aloc + kn) : (atim + (kn - 256));
          a0 = ((const float4*)ap)[0]; a1 = ((const float4*)ap)[1];
          a2 = ((const float4*)ap)[2]; a3 = ((const float4*)ap)[3];
          const float* bp = bbase + kn;
          w0 = ((const float4*)bp)[0]; w1 = ((const float4*)bp)[1];
          w2 = ((const float4*)bp)[2]; w3 = ((const float4*)bp)[3];
        }
        bf16x8 af[4], bfr[4];
#pragma unroll
        for (int i = 0; i < 4; ++i) {
          af[i]  = *(const bf16x8*)(Asl + ((wr << 6) + (i << 4) + m16) * LDR + (g4 << 3));
          bfr[i] = *(const bf16x8*)(Bsl + ((wc << 6) + (i << 4) + m16) * LDR + (g4 << 3));
        }
#pragma unroll
        for (int i = 0; i < 4; ++i)
#pragma unroll
          for (int j = 0; j < 4; ++j)
            acc[i][j] = __builtin_amdgcn_mfma_f32_16x16x32_bf16(af[i], bfr[j], acc[i][j], 0, 0, 0);
        __syncthreads();
      }
      // epilogue: L3-direct relaxed atomic stores (no L2 writeback needed for visibility)
#pragma unroll
      for (int i = 0; i < 4; ++i)
#pragma unroll
        for (int j = 0; j < 4; ++j) {
          const int col = bn + (wc << 6) + (j << 4) + m16;
          const float bv = b_ih[col];
#pragma unroll
          for (int q = 0; q < 4; ++q) {
            const int row = bm + (wr << 6) + (i << 4) + (g4 << 2) + q;
            float v = acc[i][j][q] + bv;
            __hip_atomic_store((unsigned*)(gx + (size_t)row * N + col),
                               __builtin_bit_cast(unsigned, v),
                               __ATOMIC_RELAXED, __HIP_MEMORY_SCOPE_AGENT);
          }
        }
      asm volatile("s_waitcnt vmcnt(0)" ::: "memory");   // tile stores acked at L3
      __syncthreads();
      if (tid == 0)
        __hip_atomic_fetch_add(flags + 2048 + (yt << 4), 1u,
                               __ATOMIC_RELAXED, __HIP_MEMORY_SCOPE_AGENT);
    }
    return;
  }

  // ===================== attn GEMM role (bid 192..255: 64 blocks, 512 tiles) =====================
  {
    constexpr int LDR = 40, K = 448, N = 512;
    short* Asl = smem;
    short* Bsl = smem + 128 * LDR;
    const int lane = tid & 63, wid = tid >> 6;
    const int wr = wid >> 1, wc = wid & 1;
    const int m16 = lane & 15, g4 = lane >> 4;
    const int srow = tid >> 1, shalf = tid & 1;
    for (int tile = bid - 192; tile < 512; tile += 64) {
      const int yt = tile >> 2, nt = tile & 3;
      const int bm = yt << 7, bn = nt << 7;
      f32x4 acc[4][4] = {};
      for (int k0 = 0; k0 < K; k0 += 32) {
        {
          const int grow = bm + srow;
          const int b = grow >> 8, n = grow & 255;
          const int base = b * 1024 + (n << 2);
          float4 f0, f1, f2, f3;
          if (k0 < 256) {
            const float* ap = eloc + (size_t)hloc[base] * 256 + k0 + (shalf << 4);
            f0 = ((const float4*)ap)[0]; f1 = ((const float4*)ap)[1];
            f2 = ((const float4*)ap)[2]; f3 = ((const float4*)ap)[3];
          } else if (k0 < 320) {
            const float* ap = etim + (size_t)htim[base] * 64 + (k0 - 256) + (shalf << 4);
            f0 = ((const float4*)ap)[0]; f1 = ((const float4*)ap)[1];
            f2 = ((const float4*)ap)[2]; f3 = ((const float4*)ap)[3];
          } else {
            const int cu = (k0 - 320) + (shalf << 4);
            const float4* u0 = (const float4*)(euid + (size_t)huid[base + 0] * 128 + cu);
            const float4* u1 = (const float4*)(euid + (size_t)huid[base + 1] * 128 + cu);
            const float4* u2 = (const float4*)(euid + (size_t)huid[base + 2] * 128 + cu);
            const float4* u3 = (const float4*)(euid + (size_t)huid[base + 3] * 128 + cu);
#define AVG4(idx, dst) { float4 a=u0[idx],b4=u1[idx],c4=u2[idx],d4=u3[idx];            \
            dst.x=0.25f*(a.x+b4.x+c4.x+d4.x); dst.y=0.25f*(a.y+b4.y+c4.y+d4.y);       \
            dst.z=0.25f*(a.z+b4.z+c4.z+d4.z); dst.w=0.25f*(a.w+b4.w+c4.w+d4.w); }
            AVG4(0, f0) AVG4(1, f1) AVG4(2, f2) AVG4(3, f3)
#undef AVG4
          }
          short* arow = Asl + srow * LDR + (shalf << 4);
          *(bf16x8*)(arow)     = pack8(f0, f1);
          *(bf16x8*)(arow + 8) = pack8(f2, f3);
          const float* bp = W_attn + (size_t)(bn + srow) * K + k0 + (shalf << 4);
          f0 = ((const float4*)bp)[0]; f1 = ((const float4*)bp)[1];
          f2 = ((const float4*)bp)[2]; f3 = ((const float4*)bp)[3];
          short* brow = Bsl + srow * LDR + (shalf << 4);
          *(bf16x8*)(brow)     = pack8(f0, f1);
          *(bf16x8*)(brow + 8) = pack8(f2, f3);
        }
        __syncthreads();
        bf16x8 af[4], bfr[4];
#pragma unroll
        for (int i = 0; i < 4; ++i) {
          af[i]  = *(const bf16x8*)(Asl + ((wr << 6) + (i << 4) + m16) * LDR + (g4 << 3));
          bfr[i] = *(const bf16x8*)(Bsl + ((wc << 6) + (i << 4) + m16) * LDR + (g4 << 3));
        }
#pragma unroll
        for (int i = 0; i < 4; ++i)
#pragma unroll
          for (int j = 0; j < 4; ++j)
            acc[i][j] = __builtin_amdgcn_mfma_f32_16x16x32_bf16(af[i], bfr[j], acc[i][j], 0, 0, 0);
        __syncthreads();
      }
#pragma unroll
      for (int i = 0; i < 4; ++i)
#pragma unroll
        for (int j = 0; j < 4; ++j) {
          const int col = bn + (wc << 6) + (j << 4) + m16;
          const float bv = b_attn[col];
#pragma unroll
          for (int q = 0; q < 4; ++q) {
            const int row = bm + (wr << 6) + (i << 4) + (g4 << 2) + q;
            histt[(size_t)row * N + col] = tanhf(acc[i][j][q] + bv);
          }
        }
    }
    asm volatile("s_waitcnt vmcnt(0)" ::: "memory");
    if (tid == 0)
      __hip_atomic_fetch_add(flags + 3072, 1u, __ATOMIC_RELEASE, __HIP_MEMORY_SCOPE_AGENT);

    // ---- W_final fold (consumed by NEXT launch; kernel-end flush suffices) ----
    for (int u = bid - 192; u < 5000; u += 64) {
      const int cc = tid << 1;
      float2 a = *(const float2*)(Wf + (size_t)u * 1536 + cc);
      float2 b2 = *(const float2*)(Wf + (size_t)u * 1536 + 1024 + cc);
      float2 o; o.x = a.x + b2.x; o.y = a.y + b2.y;
      *(float2*)(Wfold + (size_t)u * 512 + cc) = o;
    }
  }

  // ===================== fused attn_ctx role (bid 192..255), per-batch gated =====================
  {
    const int b = bid - 192;
    if (tid == 0) {                      // single guarded poller
      while (__hip_atomic_load(flags + 3072, __ATOMIC_RELAXED, __HIP_MEMORY_SCOPE_AGENT) < 64u)
        __builtin_amdgcn_s_sleep(7);
      while (__hip_atomic_load(flags + 1024 + (b << 4), __ATOMIC_RELAXED, __HIP_MEMORY_SCOPE_AGENT) < 16u)
        __builtin_amdgcn_s_sleep(7);
    }
    __syncthreads();
    __builtin_amdgcn_fence(__ATOMIC_ACQUIRE, "agent");
    float* ls  = (float*)smem;
    float* wv  = ls + 512;
    float* red = wv + 256;
    ((float2*)ls)[tid] = ((const float2*)(lastb + (size_t)b * 512))[tid];
    __syncthreads();
    const float* hb = histt + (size_t)b * 256 * 512;
    const float* hrow = hb + (size_t)tid * 512;
    float acc = 0.f;
    for (int k = 0; k < 512; k += 4) {
      float4 h4 = *(const float4*)(hrow + k);
      acc += ls[k] * h4.x + ls[k + 1] * h4.y + ls[k + 2] * h4.z + ls[k + 3] * h4.w;
    }
    red[tid] = acc;
    __syncthreads();
    for (int s = 128; s; s >>= 1) {
      if (tid < s) red[tid] = fmaxf(red[tid], red[tid + s]);
      __syncthreads();
    }
    float m = red[0];
    __syncthreads();
    float ex = expf(acc - m);
    wv[tid] = ex; red[tid] = ex;
    __syncthreads();
    for (int s = 128; s; s >>= 1) {
      if (tid < s) red[tid] += red[tid + s];
      __syncthreads();
    }
    float inv = 1.f / red[0];
    float c0 = 0.f, c1 = 0.f;
    for (int n = 0; n < 256; ++n) {
      float wn = wv[n];
      c0 += wn * hb[(size_t)n * 512 + tid];
      c1 += wn * hb[(size_t)n * 512 + tid + 256];
    }
    ctx[(size_t)b * 512 + tid]       = c0 * inv;
    ctx[(size_t)b * 512 + tid + 256] = c1 * inv;
  }
}

// ---------------- final (K=1024): y[b][u] = last.Wfold[u] + ctx.Wf[u,512:1024] + bf[u] ----------------
__global__ __launch_bounds__(256)
void final_gemm(const float* __restrict__ last, const float* __restrict__ ctx,
                const float* __restrict__ Wfold, const float* __restrict__ Wf,
                const float* __restrict__ bf, float* __restrict__ y) {
  __shared__ float s[64][132];
  const int tid = threadIdx.x;
  const int u0 = blockIdx.x << 3;
  const int ul = tid >> 6, b = tid & 63;
  float acc0 = 0.f, acc1 = 0.f;
  for (int kc = 0; kc < 8; ++kc) {
    __syncthreads();
    for (int i = tid; i < 2048; i += 256) {
      int rb = i >> 5, cc = (i & 31) << 2;
      int k = kc * 128 + cc;
      const float* src = (k < 512) ? (last + (size_t)rb * 512 + k)
                                   : (ctx + (size_t)rb * 512 + k - 512);
      *(float4*)&s[rb][cc] = *(const float4*)src;
    }
    __syncthreads();
#pragma unroll
    for (int uu = 0; uu < 2; ++uu) {
      int u = u0 + ul + uu * 4;
      const float* wrow = (kc < 4) ? (Wfold + (size_t)u * 512 + kc * 128)
                                   : (Wf + (size_t)u * 1536 + 512 + (kc - 4) * 128);
      float a = 0.f;
#pragma unroll 8
      for (int c = 0; c < 128; c += 4) {
        float4 w4 = *(const float4*)(wrow + c);
        float4 s4 = *(const float4*)&s[b][c];
        a += w4.x * s4.x + w4.y * s4.y + w4.z * s4.z + w4.w * s4.w;
      }
      if (uu == 0) acc0 += a; else acc1 += a;
    }
  }
  int u = u0 + ul;
  y[(size_t)b * 5000 + u]     = acc0 + bf[u];
  y[(size_t)b * 5000 + u + 4] = acc1 + bf[u + 4];
}

// ---------------- broadcast y (B,5000) -> out (B,T,5000) ----------------
__global__ void broadcast_y(const float* __restrict__ y, float* __restrict__ out) {
  int bt = blockIdx.x;
  const float4* src = (const float4*)(y + (size_t)(bt >> 7) * 5000);
  float4* dst = (float4*)(out + (size_t)bt * 5000);
  for (int i = threadIdx.x; i < 1250; i += 256) dst[i] = src[i];
}

extern "C" void kernel_launch(void* const* d_in, const int* in_sizes, int n_in,
                              void* d_out, int out_size, void* d_ws, size_t ws_size,
                              hipStream_t stream) {
  const int* loc  = (const int*)d_in[0];
  const int* tim  = (const int*)d_in[1];
  const int* lens = (const int*)d_in[2];
  const int* hloc = (const int*)d_in[3];
  const int* htim = (const int*)d_in[4];
  const int* huid = (const int*)d_in[5];
  // d_in[6] = group_size (constant 4, baked in)
  const float* eloc    = (const float*)d_in[7];
  const float* etim    = (const float*)d_in[8];
  const float* euid    = (const float*)d_in[9];
  const float* W_attn  = (const float*)d_in[10];
  const float* b_attn  = (const float*)d_in[11];
  const float* W_ih    = (const float*)d_in[12];
  const float* b_ih    = (const float*)d_in[13];
  const float* W_hh    = (const float*)d_in[14];
  const float* b_hh    = (const float*)d_in[15];
  const float* W_final = (const float*)d_in[16];
  const float* b_final = (const float*)d_in[17];
  float* out = (float*)d_out;
  char* ws = (char*)d_ws;

  // workspace layout (bytes)
  float* gx    = (float*)(ws + 0ull);            // 8192*1536*4 = 50,331,648
  float* histt = (float*)(ws + 50331648ull);     // 16384*512*4 = 33,554,432
  float* lastb = (float*)(ws + 83886080ull);     // 64*512*4 = 131,072
  float* ctx   = (float*)(ws + 84017152ull);     // 131,072
  float* yv    = (float*)(ws + 84148224ull);     // 64*5000*4 = 1,280,000
  short* h_bf  = (short*)(ws + 85428224ull);     // 2*64*512*2 = 131,072
  unsigned int* flags = (unsigned int*)(ws + 85559296ull);   // 16 KB
  float* Wfold = (float*)(ws + 85575680ull);     // 5000*512*4 = 10,240,000 (end ~95.8 MB)

  hipMemsetAsync(flags, 0, 16384, stream);
  gru_attn<<<256, 256, 0, stream>>>(W_hh, b_hh, lens, h_bf, lastb, flags,
                                    loc, tim, hloc, htim, huid, eloc, etim, euid,
                                    W_ih, b_ih, W_attn, b_attn, W_final, Wfold,
                                    gx, histt, ctx);

  final_gemm<<<625, 256, 0, stream>>>(lastb, ctx, Wfold, W_final, b_final, yv);
  broadcast_y<<<8192, 256, 0, stream>>>(yv, out);
}

// Round 17
// 602.088 us; speedup vs baseline: 1.0042x; 1.0042x over previous
//
#include <hip/hip_runtime.h>
#include <hip/hip_bf16.h>

// Sizes (fixed): B=64 T=128 HID=512 LOC_EMB=256 TIM_EMB=64 UID_EMB=128
// L_HIST=1024 G=4, K_x=320, K_attn=448, N_gates=1536, UID_SIZE=5000

typedef __attribute__((ext_vector_type(8))) short bf16x8;
typedef __attribute__((ext_vector_type(4))) float f32x4;
typedef __attribute__((ext_vector_type(4))) unsigned short u16x4;
typedef __attribute__((ext_vector_type(2))) unsigned long long u64x2;
typedef unsigned long long u64;

__device__ inline unsigned short f2bf(float x) {
  __hip_bfloat16 b = __float2bfloat16(x);
  return __builtin_bit_cast(unsigned short, b);
}
__device__ inline bf16x8 pack8(float4 a, float4 b) {
  bf16x8 w;
  w[0]=(short)f2bf(a.x); w[1]=(short)f2bf(a.y); w[2]=(short)f2bf(a.z); w[3]=(short)f2bf(a.w);
  w[4]=(short)f2bf(b.x); w[5]=(short)f2bf(b.y); w[6]=(short)f2bf(b.z); w[7]=(short)f2bf(b.w);
  return w;
}

// ---------------- gather-fused bf16 GEMM (software-pipelined): gx = [emb_loc|emb_tim] @ W_ih^T + b_ih
__global__ __launch_bounds__(256)
void gemm_gx_f(const int* __restrict__ loc, const int* __restrict__ tim,
               const float* __restrict__ eloc, const float* __restrict__ etim,
               const float* __restrict__ W_ih, const float* __restrict__ b_ih,
               float* __restrict__ gx) {
  constexpr int LDR = 40, K = 320, N = 1536;
  __shared__ short Asl[128 * LDR];
  __shared__ short Bsl[128 * LDR];
  const int tid = threadIdx.x;
  const int lane = tid & 63, wid = tid >> 6;
  const int wr = wid >> 1, wc = wid & 1;
  const int m16 = lane & 15, g4 = lane >> 4;
  const int bm = blockIdx.y * 128, bn = blockIdx.x * 128;
  const int srow = tid >> 1, shalf = tid & 1;
  const int grow = bm + srow;
  const int t_ = grow >> 6, b_ = grow & 63;
  const float* aloc = eloc + (size_t)loc[b_ * 128 + t_] * 256 + (shalf << 4);
  const float* atim = etim + (size_t)tim[b_ * 128 + t_] * 64 + (shalf << 4);
  const float* bbase = W_ih + (size_t)(bn + srow) * K + (shalf << 4);
  float4 a0, a1, a2, a3, w0, w1, w2, w3;
  {
    a0 = ((const float4*)aloc)[0]; a1 = ((const float4*)aloc)[1];
    a2 = ((const float4*)aloc)[2]; a3 = ((const float4*)aloc)[3];
    w0 = ((const float4*)bbase)[0]; w1 = ((const float4*)bbase)[1];
    w2 = ((const float4*)bbase)[2]; w3 = ((const float4*)bbase)[3];
  }
  f32x4 acc[4][4] = {};
  for (int k0 = 0; k0 < K; k0 += 32) {
    short* arow = Asl + srow * LDR + (shalf << 4);
    *(bf16x8*)(arow)     = pack8(a0, a1);
    *(bf16x8*)(arow + 8) = pack8(a2, a3);
    short* brow = Bsl + srow * LDR + (shalf << 4);
    *(bf16x8*)(brow)     = pack8(w0, w1);
    *(bf16x8*)(brow + 8) = pack8(w2, w3);
    __syncthreads();
    if (k0 + 32 < K) {
      const int kn = k0 + 32;
      const float* ap = (kn < 256) ? (aloc + kn) : (atim + (kn - 256));
      a0 = ((const float4*)ap)[0]; a1 = ((const float4*)ap)[1];
      a2 = ((const float4*)ap)[2]; a3 = ((const float4*)ap)[3];
      const float* bp = bbase + kn;
      w0 = ((const float4*)bp)[0]; w1 = ((const float4*)bp)[1];
      w2 = ((const float4*)bp)[2]; w3 = ((const float4*)bp)[3];
    }
    bf16x8 af[4], bfr[4];
#pragma unroll
    for (int i = 0; i < 4; ++i) {
      af[i]  = *(const bf16x8*)(Asl + ((wr << 6) + (i << 4) + m16) * LDR + (g4 << 3));
      bfr[i] = *(const bf16x8*)(Bsl + ((wc << 6) + (i << 4) + m16) * LDR + (g4 << 3));
    }
#pragma unroll
    for (int i = 0; i < 4; ++i)
#pragma unroll
      for (int j = 0; j < 4; ++j)
        acc[i][j] = __builtin_amdgcn_mfma_f32_16x16x32_bf16(af[i], bfr[j], acc[i][j], 0, 0, 0);
    __syncthreads();
  }
#pragma unroll
  for (int i = 0; i < 4; ++i)
#pragma unroll
    for (int j = 0; j < 4; ++j) {
      const int col = bn + (wc << 6) + (j << 4) + m16;
      const float bv = b_ih[col];
#pragma unroll
      for (int q = 0; q < 4; ++q) {
        const int row = bm + (wr << 6) + (i << 4) + (g4 << 2) + q;
        gx[(size_t)row * N + col] = acc[i][j][q] + bv;
      }
    }
}

// ---------------- combined: GRU (0..63) + attn GEMM+fold (64..191) + fused ctx (64..127)
// sync dwords: [0,2048)    GRU per-WAVE flags (4 grp x 32 waves x 16dw)
//              [2048,3072) batchdone[b] (64 x 16dw; ==32 when lastb[b] final)
//              [3072]      histt_done (128 attn blocks)
// GRU: per-wave flags, ZERO barriers (each wave owns its LDS slabs / 16 j-rows / flag).
// producer wave: h stores -> vmcnt(0) -> own flag (lane 0). consumer: poll 32 flags -> h loads.
__global__ __launch_bounds__(256)
void gru_attn(const float* __restrict__ gx, const float* __restrict__ W_hh,
              const float* __restrict__ b_hh, const int* __restrict__ lens,
              short* __restrict__ h_bf, float* __restrict__ lastb,
              unsigned int* __restrict__ flags,
              const int* __restrict__ hloc, const int* __restrict__ htim,
              const int* __restrict__ huid,
              const float* __restrict__ eloc, const float* __restrict__ etim,
              const float* __restrict__ euid,
              const float* __restrict__ W_attn, const float* __restrict__ b_attn,
              const float* __restrict__ Wf, float* __restrict__ Wfold,
              float* __restrict__ histt, float* __restrict__ ctx) {
  __shared__ short smem[6 * 16 * 512];   // 96 KB shared by all roles
  const int bid = blockIdx.x;
  const int tid = threadIdx.x;

  if (bid < 64) {
    // ===================== GRU role (2 active waves, no barriers) =====================
    if (tid >= 128) return;
    const int grp = bid & 3;
    const int b0 = grp << 4;
    int tmax = 0;
    for (int i = 0; i < 16; ++i) tmax = max(tmax, lens[b0 + i]);   // group-uniform

    const int lane = tid & 63, tt = tid >> 6;
    const int c = bid >> 2;
    const int j0 = (c << 5) + (tt << 4);
    const int m16 = lane & 15, g4 = lane >> 4;

    // own weight slabs only -> no barrier needed
    for (int gi = 0; gi < 3; ++gi) {
      const float* wg = W_hh + (size_t)(gi * 512 + j0) * 512;
      short* slab = smem + (((gi << 1) + tt) << 13);
      for (int r = 0; r < 16; ++r) {
        int k = lane << 3;
        const float4* src = (const float4*)(wg + (size_t)r * 512 + k);
        int off = ((r << 9) + k) ^ ((r & 7) << 3);
        *(bf16x8*)(slab + off) = pack8(src[0], src[1]);
      }
    }

    const int bcol = b0 + m16;
    const int jr = j0 + (g4 << 2);
    const f32x4 bhr = *(const f32x4*)&b_hh[jr];
    const f32x4 bhz = *(const f32x4*)&b_hh[512 + jr];
    const f32x4 bhn = *(const f32x4*)&b_hh[1024 + jr];
    const int lenb = lens[bcol];
    f32x4 hprev = {0.f, 0.f, 0.f, 0.f};

    unsigned int* gflags = flags + (grp << 9);               // 32 waves x 16 dwords
    unsigned int* ownflag = gflags + (((c << 1) + tt) << 4);
    unsigned int* bdone = flags + 2048;

    for (int t = 0; t < tmax; ++t) {
      const float* gxb = gx + ((size_t)t * 64 + bcol) * 1536;
      f32x4 gr = *(const f32x4*)(gxb + jr);
      f32x4 gz = *(const f32x4*)(gxb + 512 + jr);
      f32x4 gn = *(const f32x4*)(gxb + 1024 + jr);
      f32x4 ar = {0.f, 0.f, 0.f, 0.f}, az = ar, an = ar;
      if (t) {
        unsigned tgt = (unsigned)t;
        while (true) {
          unsigned f = tgt;
          if (lane < 32)
            f = __hip_atomic_load(gflags + (lane << 4), __ATOMIC_RELAXED, __HIP_MEMORY_SCOPE_AGENT);
          if (__all((int)(f >= tgt))) break;
        }
        asm volatile("" ::: "memory");

        const u64* hp = (const u64*)(h_bf + ((t & 1) << 15) + (size_t)bcol * 512 + (g4 << 3));
        u64 hu[32];
#pragma unroll
        for (int ks = 0; ks < 16; ++ks) {
          hu[2 * ks]     = __hip_atomic_load(hp + ks * 8,     __ATOMIC_RELAXED, __HIP_MEMORY_SCOPE_AGENT);
          hu[2 * ks + 1] = __hip_atomic_load(hp + ks * 8 + 1, __ATOMIC_RELAXED, __HIP_MEMORY_SCOPE_AGENT);
        }
#define GRU_MFMA(ks)                                                                 \
        {                                                                            \
          u64x2 p; p[0] = hu[2 * (ks)]; p[1] = hu[2 * (ks) + 1];                     \
          bf16x8 hf = __builtin_bit_cast(bf16x8, p);                                 \
          int off = ((m16 << 9) + ((ks) << 5) + (g4 << 3)) ^ ((m16 & 7) << 3);       \
          ar = __builtin_amdgcn_mfma_f32_16x16x32_bf16(*(const bf16x8*)(smem + ((0 + tt) << 13) + off), hf, ar, 0, 0, 0); \
          az = __builtin_amdgcn_mfma_f32_16x16x32_bf16(*(const bf16x8*)(smem + ((2 + tt) << 13) + off), hf, az, 0, 0, 0); \
          an = __builtin_amdgcn_mfma_f32_16x16x32_bf16(*(const bf16x8*)(smem + ((4 + tt) << 13) + off), hf, an, 0, 0, 0); \
        }
        GRU_MFMA(0)  GRU_MFMA(1)  GRU_MFMA(2)  GRU_MFMA(3)
        GRU_MFMA(4)  GRU_MFMA(5)  GRU_MFMA(6)  GRU_MFMA(7)
        GRU_MFMA(8)  GRU_MFMA(9)  GRU_MFMA(10) GRU_MFMA(11)
        GRU_MFMA(12) GRU_MFMA(13) GRU_MFMA(14) GRU_MFMA(15)
#undef GRU_MFMA
      }
      u16x4 hw;
#pragma unroll
      for (int q = 0; q < 4; ++q) {
        float r = 1.f / (1.f + __expf(-(gr[q] + ar[q] + bhr[q])));
        float z = 1.f / (1.f + __expf(-(gz[q] + az[q] + bhz[q])));
        float xn = gn[q] + r * (an[q] + bhn[q]);
        float n = 1.f - 2.f / (__expf(2.f * xn) + 1.f);
        float hv = (1.f - z) * n + z * hprev[q];
        hprev[q] = hv;
        hw[q] = f2bf(hv);
      }
      __hip_atomic_store((u64*)(h_bf + ((~t & 1) << 15) + (size_t)bcol * 512 + jr),
                         __builtin_bit_cast(u64, hw),
                         __ATOMIC_RELAXED, __HIP_MEMORY_SCOPE_AGENT);
      if (t == lenb - 1) {
        *(f32x4*)(lastb + (size_t)bcol * 512 + jr) = hprev;
      }
      if (t < tmax - 1) {
        asm volatile("s_waitcnt vmcnt(0)" ::: "memory");   // own h + lastb stores acked at L3
        if (lane == 0) {
          __hip_atomic_store(ownflag, (unsigned)(t + 1), __ATOMIC_RELAXED, __HIP_MEMORY_SCOPE_AGENT);
          for (int i = 0; i < 16; ++i)
            if (lens[b0 + i] == t + 1)
              __hip_atomic_fetch_add(bdone + ((b0 + i) << 4), 1u,
                                     __ATOMIC_RELAXED, __HIP_MEMORY_SCOPE_AGENT);
        }
      }
    }
    // epilogue: drain last step's stores, signal final batches (per wave)
    asm volatile("s_waitcnt vmcnt(0)" ::: "memory");
    if (lane == 0) {
      for (int i = 0; i < 16; ++i)
        if (lens[b0 + i] == tmax)
          __hip_atomic_fetch_add(bdone + ((b0 + i) << 4), 1u,
                                 __ATOMIC_RELAXED, __HIP_MEMORY_SCOPE_AGENT);
    }
    return;
  }

  // ===================== attn GEMM role (bid 64..191) =====================
  {
    constexpr int LDR = 40, K = 448, N = 512;
    short* Asl = smem;
    short* Bsl = smem + 128 * LDR;
    const int lane = tid & 63, wid = tid >> 6;
    const int wr = wid >> 1, wc = wid & 1;
    const int m16 = lane & 15, g4 = lane >> 4;
    const int srow = tid >> 1, shalf = tid & 1;
    for (int tile = bid - 64; tile < 512; tile += 128) {
      const int yt = tile >> 2, nt = tile & 3;
      const int bm = yt << 7, bn = nt << 7;
      f32x4 acc[4][4] = {};
      for (int k0 = 0; k0 < K; k0 += 32) {
        {
          const int grow = bm + srow;
          const int b = grow >> 8, n = grow & 255;
          const int base = b * 1024 + (n << 2);
          float4 f0, f1, f2, f3;
          if (k0 < 256) {
            const float* ap = eloc + (size_t)hloc[base] * 256 + k0 + (shalf << 4);
            f0 = ((const float4*)ap)[0]; f1 = ((const float4*)ap)[1];
            f2 = ((const float4*)ap)[2]; f3 = ((const float4*)ap)[3];
          } else if (k0 < 320) {
            const float* ap = etim + (size_t)htim[base] * 64 + (k0 - 256) + (shalf << 4);
            f0 = ((const float4*)ap)[0]; f1 = ((const float4*)ap)[1];
            f2 = ((const float4*)ap)[2]; f3 = ((const float4*)ap)[3];
          } else {
            const int cu = (k0 - 320) + (shalf << 4);
            const float4* u0 = (const float4*)(euid + (size_t)huid[base + 0] * 128 + cu);
            const float4* u1 = (const float4*)(euid + (size_t)huid[base + 1] * 128 + cu);
            const float4* u2 = (const float4*)(euid + (size_t)huid[base + 2] * 128 + cu);
            const float4* u3 = (const float4*)(euid + (size_t)huid[base + 3] * 128 + cu);
#define AVG4(idx, dst) { float4 a=u0[idx],b4=u1[idx],c4=u2[idx],d4=u3[idx];            \
            dst.x=0.25f*(a.x+b4.x+c4.x+d4.x); dst.y=0.25f*(a.y+b4.y+c4.y+d4.y);       \
            dst.z=0.25f*(a.z+b4.z+c4.z+d4.z); dst.w=0.25f*(a.w+b4.w+c4.w+d4.w); }
            AVG4(0, f0) AVG4(1, f1) AVG4(2, f2) AVG4(3, f3)
#undef AVG4
          }
          short* arow = Asl + srow * LDR + (shalf << 4);
          *(bf16x8*)(arow)     = pack8(f0, f1);
          *(bf16x8*)(arow + 8) = pack8(f2, f3);
          const float* bp = W_attn + (size_t)(bn + srow) * K + k0 + (shalf << 4);
          f0 = ((const float4*)bp)[0]; f1 = ((const float4*)bp)[1];
          f2 = ((const float4*)bp)[2]; f3 = ((const float4*)bp)[3];
          short* brow = Bsl + srow * LDR + (shalf << 4);
          *(bf16x8*)(brow)     = pack8(f0, f1);
          *(bf16x8*)(brow + 8) = pack8(f2, f3);
        }
        __syncthreads();
        bf16x8 af[4], bfr[4];
#pragma unroll
        for (int i = 0; i < 4; ++i) {
          af[i]  = *(const bf16x8*)(Asl + ((wr << 6) + (i << 4) + m16) * LDR + (g4 << 3));
          bfr[i] = *(const bf16x8*)(Bsl + ((wc << 6) + (i << 4) + m16) * LDR + (g4 << 3));
        }
#pragma unroll
        for (int i = 0; i < 4; ++i)
#pragma unroll
          for (int j = 0; j < 4; ++j)
            acc[i][j] = __builtin_amdgcn_mfma_f32_16x16x32_bf16(af[i], bfr[j], acc[i][j], 0, 0, 0);
        __syncthreads();
      }
#pragma unroll
      for (int i = 0; i < 4; ++i)
#pragma unroll
        for (int j = 0; j < 4; ++j) {
          const int col = bn + (wc << 6) + (j << 4) + m16;
          const float bv = b_attn[col];
#pragma unroll
          for (int q = 0; q < 4; ++q) {
            const int row = bm + (wr << 6) + (i << 4) + (g4 << 2) + q;
            histt[(size_t)row * N + col] = tanhf(acc[i][j][q] + bv);
          }
        }
    }
    asm volatile("s_waitcnt vmcnt(0)" ::: "memory");
    if (tid == 0)
      __hip_atomic_fetch_add(flags + 3072, 1u, __ATOMIC_RELEASE, __HIP_MEMORY_SCOPE_AGENT);

    // ---- W_final fold (consumed by NEXT launch; kernel-end flush suffices) ----
    for (int u = bid - 64; u < 5000; u += 128) {
      const int cc = tid << 1;
      float2 a = *(const float2*)(Wf + (size_t)u * 1536 + cc);
      float2 b2 = *(const float2*)(Wf + (size_t)u * 1536 + 1024 + cc);
      float2 o; o.x = a.x + b2.x; o.y = a.y + b2.y;
      *(float2*)(Wfold + (size_t)u * 512 + cc) = o;
    }
  }

  // ===================== fused attn_ctx role (bid 64..127), per-batch gated =====================
  if (bid < 128) {
    const int b = bid - 64;
    if (tid == 0) {                      // single guarded poller
      while (__hip_atomic_load(flags + 3072, __ATOMIC_RELAXED, __HIP_MEMORY_SCOPE_AGENT) < 128u)
        __builtin_amdgcn_s_sleep(7);
      while (__hip_atomic_load(flags + 2048 + (b << 4), __ATOMIC_RELAXED, __HIP_MEMORY_SCOPE_AGENT) < 32u)
        __builtin_amdgcn_s_sleep(7);
    }
    __syncthreads();
    __builtin_amdgcn_fence(__ATOMIC_ACQUIRE, "agent");
    float* ls  = (float*)smem;
    float* wv  = ls + 512;
    float* red = wv + 256;
    ((float2*)ls)[tid] = ((const float2*)(lastb + (size_t)b * 512))[tid];
    __syncthreads();
    const float* hb = histt + (size_t)b * 256 * 512;
    const float* hrow = hb + (size_t)tid * 512;
    float acc = 0.f;
    for (int k = 0; k < 512; k += 4) {
      float4 h4 = *(const float4*)(hrow + k);
      acc += ls[k] * h4.x + ls[k + 1] * h4.y + ls[k + 2] * h4.z + ls[k + 3] * h4.w;
    }
    red[tid] = acc;
    __syncthreads();
    for (int s = 128; s; s >>= 1) {
      if (tid < s) red[tid] = fmaxf(red[tid], red[tid + s]);
      __syncthreads();
    }
    float m = red[0];
    __syncthreads();
    float ex = expf(acc - m);
    wv[tid] = ex; red[tid] = ex;
    __syncthreads();
    for (int s = 128; s; s >>= 1) {
      if (tid < s) red[tid] += red[tid + s];
      __syncthreads();
    }
    float inv = 1.f / red[0];
    float c0 = 0.f, c1 = 0.f;
    for (int n = 0; n < 256; ++n) {
      float wn = wv[n];
      c0 += wn * hb[(size_t)n * 512 + tid];
      c1 += wn * hb[(size_t)n * 512 + tid + 256];
    }
    ctx[(size_t)b * 512 + tid]       = c0 * inv;
    ctx[(size_t)b * 512 + tid + 256] = c1 * inv;
  }
}

// ---------------- final (K=1024): y[b][u] = last.Wfold[u] + ctx.Wf[u,512:1024] + bf[u] ----------------
__global__ __launch_bounds__(256)
void final_gemm(const float* __restrict__ last, const float* __restrict__ ctx,
                const float* __restrict__ Wfold, const float* __restrict__ Wf,
                const float* __restrict__ bf, float* __restrict__ y) {
  __shared__ float s[64][132];
  const int tid = threadIdx.x;
  const int u0 = blockIdx.x << 3;
  const int ul = tid >> 6, b = tid & 63;
  float acc0 = 0.f, acc1 = 0.f;
  for (int kc = 0; kc < 8; ++kc) {
    __syncthreads();
    for (int i = tid; i < 2048; i += 256) {
      int rb = i >> 5, cc = (i & 31) << 2;
      int k = kc * 128 + cc;
      const float* src = (k < 512) ? (last + (size_t)rb * 512 + k)
                                   : (ctx + (size_t)rb * 512 + k - 512);
      *(float4*)&s[rb][cc] = *(const float4*)src;
    }
    __syncthreads();
#pragma unroll
    for (int uu = 0; uu < 2; ++uu) {
      int u = u0 + ul + uu * 4;
      const float* wrow = (kc < 4) ? (Wfold + (size_t)u * 512 + kc * 128)
                                   : (Wf + (size_t)u * 1536 + 512 + (kc - 4) * 128);
      float a = 0.f;
#pragma unroll 8
      for (int c = 0; c < 128; c += 4) {
        float4 w4 = *(const float4*)(wrow + c);
        float4 s4 = *(const float4*)&s[b][c];
        a += w4.x * s4.x + w4.y * s4.y + w4.z * s4.z + w4.w * s4.w;
      }
      if (uu == 0) acc0 += a; else acc1 += a;
    }
  }
  int u = u0 + ul;
  y[(size_t)b * 5000 + u]     = acc0 + bf[u];
  y[(size_t)b * 5000 + u + 4] = acc1 + bf[u + 4];
}

// ---------------- broadcast y (B,5000) -> out (B,T,5000) ----------------
__global__ void broadcast_y(const float* __restrict__ y, float* __restrict__ out) {
  int bt = blockIdx.x;
  const float4* src = (const float4*)(y + (size_t)(bt >> 7) * 5000);
  float4* dst = (float4*)(out + (size_t)bt * 5000);
  for (int i = threadIdx.x; i < 1250; i += 256) dst[i] = src[i];
}

extern "C" void kernel_launch(void* const* d_in, const int* in_sizes, int n_in,
                              void* d_out, int out_size, void* d_ws, size_t ws_size,
                              hipStream_t stream) {
  const int* loc  = (const int*)d_in[0];
  const int* tim  = (const int*)d_in[1];
  const int* lens = (const int*)d_in[2];
  const int* hloc = (const int*)d_in[3];
  const int* htim = (const int*)d_in[4];
  const int* huid = (const int*)d_in[5];
  // d_in[6] = group_size (constant 4, baked in)
  const float* eloc    = (const float*)d_in[7];
  const float* etim    = (const float*)d_in[8];
  const float* euid    = (const float*)d_in[9];
  const float* W_attn  = (const float*)d_in[10];
  const float* b_attn  = (const float*)d_in[11];
  const float* W_ih    = (const float*)d_in[12];
  const float* b_ih    = (const float*)d_in[13];
  const float* W_hh    = (const float*)d_in[14];
  const float* b_hh    = (const float*)d_in[15];
  const float* W_final = (const float*)d_in[16];
  const float* b_final = (const float*)d_in[17];
  float* out = (float*)d_out;
  char* ws = (char*)d_ws;

  // workspace layout (bytes)
  float* gx    = (float*)(ws + 0ull);            // 8192*1536*4 = 50,331,648
  float* histt = (float*)(ws + 50331648ull);     // 16384*512*4 = 33,554,432
  float* lastb = (float*)(ws + 83886080ull);     // 64*512*4 = 131,072
  float* ctx   = (float*)(ws + 84017152ull);     // 131,072
  float* yv    = (float*)(ws + 84148224ull);     // 64*5000*4 = 1,280,000
  short* h_bf  = (short*)(ws + 85428224ull);     // 2*64*512*2 = 131,072
  unsigned int* flags = (unsigned int*)(ws + 85559296ull);   // 16 KB
  float* Wfold = (float*)(ws + 85575680ull);     // 5000*512*4 = 10,240,000 (end ~95.8 MB)

  hipMemsetAsync(flags, 0, 16384, stream);       // before gemm: off the critical path
  gemm_gx_f<<<dim3(12, 64), 256, 0, stream>>>(loc, tim, eloc, etim, W_ih, b_ih, gx);

  gru_attn<<<192, 256, 0, stream>>>(gx, W_hh, b_hh, lens, h_bf, lastb, flags,
                                    hloc, htim, huid, eloc, etim, euid,
                                    W_attn, b_attn, W_final, Wfold, histt, ctx);

  final_gemm<<<625, 256, 0, stream>>>(lastb, ctx, Wfold, W_final, b_final, yv);
  broadcast_y<<<8192, 256, 0, stream>>>(yv, out);
}

// Round 18
// 591.204 us; speedup vs baseline: 1.0226x; 1.0184x over previous
//
#include <hip/hip_runtime.h>
#include <hip/hip_bf16.h>

// Sizes (fixed): B=64 T=128 HID=512 LOC_EMB=256 TIM_EMB=64 UID_EMB=128
// L_HIST=1024 G=4, K_x=320, K_attn=448, N_gates=1536, UID_SIZE=5000

typedef __attribute__((ext_vector_type(8))) short bf16x8;
typedef __attribute__((ext_vector_type(4))) float f32x4;
typedef __attribute__((ext_vector_type(4))) unsigned short u16x4;
typedef __attribute__((ext_vector_type(2))) unsigned long long u64x2;
typedef unsigned long long u64;

__device__ inline unsigned short f2bf(float x) {
  __hip_bfloat16 b = __float2bfloat16(x);
  return __builtin_bit_cast(unsigned short, b);
}
__device__ inline bf16x8 pack8(float4 a, float4 b) {
  bf16x8 w;
  w[0]=(short)f2bf(a.x); w[1]=(short)f2bf(a.y); w[2]=(short)f2bf(a.z); w[3]=(short)f2bf(a.w);
  w[4]=(short)f2bf(b.x); w[5]=(short)f2bf(b.y); w[6]=(short)f2bf(b.z); w[7]=(short)f2bf(b.w);
  return w;
}
__device__ inline f32x4 bf4_to_f32(u16x4 v) {
  f32x4 o;
#pragma unroll
  for (int q = 0; q < 4; ++q)
    o[q] = __builtin_bit_cast(float, ((unsigned)v[q]) << 16);
  return o;
}

// ---------------- gather-fused bf16 GEMM (software-pipelined): gx(bf16) = [emb_loc|emb_tim] @ W_ih^T + b_ih
__global__ __launch_bounds__(256)
void gemm_gx_f(const int* __restrict__ loc, const int* __restrict__ tim,
               const float* __restrict__ eloc, const float* __restrict__ etim,
               const float* __restrict__ W_ih, const float* __restrict__ b_ih,
               short* __restrict__ gxb) {
  constexpr int LDR = 40, K = 320, N = 1536;
  __shared__ short Asl[128 * LDR];
  __shared__ short Bsl[128 * LDR];
  const int tid = threadIdx.x;
  const int lane = tid & 63, wid = tid >> 6;
  const int wr = wid >> 1, wc = wid & 1;
  const int m16 = lane & 15, g4 = lane >> 4;
  const int bm = blockIdx.y * 128, bn = blockIdx.x * 128;
  const int srow = tid >> 1, shalf = tid & 1;
  const int grow = bm + srow;
  const int t_ = grow >> 6, b_ = grow & 63;
  const float* aloc = eloc + (size_t)loc[b_ * 128 + t_] * 256 + (shalf << 4);
  const float* atim = etim + (size_t)tim[b_ * 128 + t_] * 64 + (shalf << 4);
  const float* bbase = W_ih + (size_t)(bn + srow) * K + (shalf << 4);
  float4 a0, a1, a2, a3, w0, w1, w2, w3;
  {
    a0 = ((const float4*)aloc)[0]; a1 = ((const float4*)aloc)[1];
    a2 = ((const float4*)aloc)[2]; a3 = ((const float4*)aloc)[3];
    w0 = ((const float4*)bbase)[0]; w1 = ((const float4*)bbase)[1];
    w2 = ((const float4*)bbase)[2]; w3 = ((const float4*)bbase)[3];
  }
  f32x4 acc[4][4] = {};
  for (int k0 = 0; k0 < K; k0 += 32) {
    short* arow = Asl + srow * LDR + (shalf << 4);
    *(bf16x8*)(arow)     = pack8(a0, a1);
    *(bf16x8*)(arow + 8) = pack8(a2, a3);
    short* brow = Bsl + srow * LDR + (shalf << 4);
    *(bf16x8*)(brow)     = pack8(w0, w1);
    *(bf16x8*)(brow + 8) = pack8(w2, w3);
    __syncthreads();
    if (k0 + 32 < K) {
      const int kn = k0 + 32;
      const float* ap = (kn < 256) ? (aloc + kn) : (atim + (kn - 256));
      a0 = ((const float4*)ap)[0]; a1 = ((const float4*)ap)[1];
      a2 = ((const float4*)ap)[2]; a3 = ((const float4*)ap)[3];
      const float* bp = bbase + kn;
      w0 = ((const float4*)bp)[0]; w1 = ((const float4*)bp)[1];
      w2 = ((const float4*)bp)[2]; w3 = ((const float4*)bp)[3];
    }
    bf16x8 af[4], bfr[4];
#pragma unroll
    for (int i = 0; i < 4; ++i) {
      af[i]  = *(const bf16x8*)(Asl + ((wr << 6) + (i << 4) + m16) * LDR + (g4 << 3));
      bfr[i] = *(const bf16x8*)(Bsl + ((wc << 6) + (i << 4) + m16) * LDR + (g4 << 3));
    }
#pragma unroll
    for (int i = 0; i < 4; ++i)
#pragma unroll
      for (int j = 0; j < 4; ++j)
        acc[i][j] = __builtin_amdgcn_mfma_f32_16x16x32_bf16(af[i], bfr[j], acc[i][j], 0, 0, 0);
    __syncthreads();
  }
#pragma unroll
  for (int i = 0; i < 4; ++i)
#pragma unroll
    for (int j = 0; j < 4; ++j) {
      const int col = bn + (wc << 6) + (j << 4) + m16;
      const float bv = b_ih[col];
#pragma unroll
      for (int q = 0; q < 4; ++q) {
        const int row = bm + (wr << 6) + (i << 4) + (g4 << 2) + q;
        gxb[(size_t)row * N + col] = (short)f2bf(acc[i][j][q] + bv);
      }
    }
}

// ---------------- combined: GRU (0..63) + attn GEMM+fold (64..191) + fused ctx (64..127)
// sync dwords: [0,1024)    GRU block flags (4 grp x 16 blocks x 16dw)
//              [1024,2048) batchdone[b] (64 x 16dw; ==16 when lastb[b] final)
//              [2048]      histt_done (128 attn blocks)
// GRU (r15-proven): block flags + per-step 2-wave __syncthreads join; gx read as bf16.
__global__ __launch_bounds__(256)
void gru_attn(const short* __restrict__ gxb, const float* __restrict__ W_hh,
              const float* __restrict__ b_hh, const int* __restrict__ lens,
              short* __restrict__ h_bf, float* __restrict__ lastb,
              unsigned int* __restrict__ flags,
              const int* __restrict__ hloc, const int* __restrict__ htim,
              const int* __restrict__ huid,
              const float* __restrict__ eloc, const float* __restrict__ etim,
              const float* __restrict__ euid,
              const float* __restrict__ W_attn, const float* __restrict__ b_attn,
              const float* __restrict__ Wf, float* __restrict__ Wfold,
              float* __restrict__ histt, float* __restrict__ ctx) {
  __shared__ short smem[6 * 16 * 512];   // 96 KB shared by all roles
  const int bid = blockIdx.x;
  const int tid = threadIdx.x;

  if (bid < 64) {
    // ===================== GRU role =====================
    const int grp0 = bid & 3;
    const int b00 = grp0 << 4;
    int tmax = 0;
    for (int i = 0; i < 16; ++i) tmax = max(tmax, lens[b00 + i]);   // group-uniform

    if (tid >= 128) {                    // idle waves: match barrier count exactly
      for (int t = 0; t < tmax + 1; ++t) __syncthreads();
      return;
    }
    const int lane = tid & 63, tt = tid >> 6;
    const int c = bid >> 2, grp = grp0;
    const int j0 = (c << 5) + (tt << 4);
    const int b0 = b00;
    const int m16 = lane & 15, g4 = lane >> 4;

    for (int gi = 0; gi < 3; ++gi) {
      const float* wg = W_hh + (size_t)(gi * 512 + j0) * 512;
      short* slab = smem + (((gi << 1) + tt) << 13);
      for (int r = 0; r < 16; ++r) {
        int k = lane << 3;
        const float4* src = (const float4*)(wg + (size_t)r * 512 + k);
        int off = ((r << 9) + k) ^ ((r & 7) << 3);
        *(bf16x8*)(slab + off) = pack8(src[0], src[1]);
      }
    }
    __syncthreads();                     // barrier 1

    const int bcol = b0 + m16;
    const int jr = j0 + (g4 << 2);
    const f32x4 bhr = *(const f32x4*)&b_hh[jr];
    const f32x4 bhz = *(const f32x4*)&b_hh[512 + jr];
    const f32x4 bhn = *(const f32x4*)&b_hh[1024 + jr];
    const int lenb = lens[bcol];
    f32x4 hprev = {0.f, 0.f, 0.f, 0.f};

    unsigned int* gflags = flags + (grp << 8);
    unsigned int* ownflag = gflags + (c << 4);
    unsigned int* bdone = flags + 1024;

    for (int t = 0; t < tmax; ++t) {
      const short* gxp = gxb + ((size_t)t * 64 + bcol) * 1536;
      u16x4 g0 = *(const u16x4*)(gxp + jr);
      u16x4 g1 = *(const u16x4*)(gxp + 512 + jr);
      u16x4 g2 = *(const u16x4*)(gxp + 1024 + jr);
      f32x4 gr = bf4_to_f32(g0);
      f32x4 gz = bf4_to_f32(g1);
      f32x4 gn = bf4_to_f32(g2);
      f32x4 ar = {0.f, 0.f, 0.f, 0.f}, az = ar, an = ar;
      if (t) {
        unsigned tgt = (unsigned)t;
        while (true) {
          unsigned f = tgt;
          if (lane < 16)
            f = __hip_atomic_load(gflags + (lane << 4), __ATOMIC_RELAXED, __HIP_MEMORY_SCOPE_AGENT);
          if (__all((int)(f >= tgt))) break;
        }
        asm volatile("" ::: "memory");

        const u64* hp = (const u64*)(h_bf + ((t & 1) << 15) + (size_t)bcol * 512 + (g4 << 3));
        u64 hu[32];
#pragma unroll
        for (int ks = 0; ks < 16; ++ks) {
          hu[2 * ks]     = __hip_atomic_load(hp + ks * 8,     __ATOMIC_RELAXED, __HIP_MEMORY_SCOPE_AGENT);
          hu[2 * ks + 1] = __hip_atomic_load(hp + ks * 8 + 1, __ATOMIC_RELAXED, __HIP_MEMORY_SCOPE_AGENT);
        }
#define GRU_MFMA(ks)                                                                 \
        {                                                                            \
          u64x2 p; p[0] = hu[2 * (ks)]; p[1] = hu[2 * (ks) + 1];                     \
          bf16x8 hf = __builtin_bit_cast(bf16x8, p);                                 \
          int off = ((m16 << 9) + ((ks) << 5) + (g4 << 3)) ^ ((m16 & 7) << 3);       \
          ar = __builtin_amdgcn_mfma_f32_16x16x32_bf16(*(const bf16x8*)(smem + ((0 + tt) << 13) + off), hf, ar, 0, 0, 0); \
          az = __builtin_amdgcn_mfma_f32_16x16x32_bf16(*(const bf16x8*)(smem + ((2 + tt) << 13) + off), hf, az, 0, 0, 0); \
          an = __builtin_amdgcn_mfma_f32_16x16x32_bf16(*(const bf16x8*)(smem + ((4 + tt) << 13) + off), hf, an, 0, 0, 0); \
        }
        GRU_MFMA(0)  GRU_MFMA(1)  GRU_MFMA(2)  GRU_MFMA(3)
        GRU_MFMA(4)  GRU_MFMA(5)  GRU_MFMA(6)  GRU_MFMA(7)
        GRU_MFMA(8)  GRU_MFMA(9)  GRU_MFMA(10) GRU_MFMA(11)
        GRU_MFMA(12) GRU_MFMA(13) GRU_MFMA(14) GRU_MFMA(15)
#undef GRU_MFMA
      }
      u16x4 hw;
#pragma unroll
      for (int q = 0; q < 4; ++q) {
        float r = 1.f / (1.f + __expf(-(gr[q] + ar[q] + bhr[q])));
        float z = 1.f / (1.f + __expf(-(gz[q] + az[q] + bhz[q])));
        float xn = gn[q] + r * (an[q] + bhn[q]);
        float n = 1.f - 2.f / (__expf(2.f * xn) + 1.f);
        float hv = (1.f - z) * n + z * hprev[q];
        hprev[q] = hv;
        hw[q] = f2bf(hv);
      }
      __hip_atomic_store((u64*)(h_bf + ((~t & 1) << 15) + (size_t)bcol * 512 + jr),
                         __builtin_bit_cast(u64, hw),
                         __ATOMIC_RELAXED, __HIP_MEMORY_SCOPE_AGENT);
      if (t == lenb - 1) {
        *(f32x4*)(lastb + (size_t)bcol * 512 + jr) = hprev;
      }
      if (t < tmax - 1) {
        asm volatile("s_waitcnt vmcnt(0)" ::: "memory");   // h + lastb stores acked
        __syncthreads();                                   // barriers 2..tmax
        if (tid == 0) {
          __hip_atomic_store(ownflag, (unsigned)(t + 1), __ATOMIC_RELAXED, __HIP_MEMORY_SCOPE_AGENT);
          for (int i = 0; i < 16; ++i)
            if (lens[b0 + i] == t + 1)
              __hip_atomic_fetch_add(bdone + ((b0 + i) << 4), 1u,
                                     __ATOMIC_RELAXED, __HIP_MEMORY_SCOPE_AGENT);
        }
      }
    }
    asm volatile("s_waitcnt vmcnt(0)" ::: "memory");
    __syncthreads();                     // barrier tmax+1
    if (tid == 0) {
      for (int i = 0; i < 16; ++i)
        if (lens[b0 + i] == tmax)
          __hip_atomic_fetch_add(flags + 1024 + ((b0 + i) << 4), 1u,
                                 __ATOMIC_RELAXED, __HIP_MEMORY_SCOPE_AGENT);
    }
    return;
  }

  // ===================== attn GEMM role (bid 64..191) =====================
  {
    constexpr int LDR = 40, K = 448, N = 512;
    short* Asl = smem;
    short* Bsl = smem + 128 * LDR;
    const int lane = tid & 63, wid = tid >> 6;
    const int wr = wid >> 1, wc = wid & 1;
    const int m16 = lane & 15, g4 = lane >> 4;
    const int srow = tid >> 1, shalf = tid & 1;
    for (int tile = bid - 64; tile < 512; tile += 128) {
      const int yt = tile >> 2, nt = tile & 3;
      const int bm = yt << 7, bn = nt << 7;
      f32x4 acc[4][4] = {};
      for (int k0 = 0; k0 < K; k0 += 32) {
        {
          const int grow = bm + srow;
          const int b = grow >> 8, n = grow & 255;
          const int base = b * 1024 + (n << 2);
          float4 f0, f1, f2, f3;
          if (k0 < 256) {
            const float* ap = eloc + (size_t)hloc[base] * 256 + k0 + (shalf << 4);
            f0 = ((const float4*)ap)[0]; f1 = ((const float4*)ap)[1];
            f2 = ((const float4*)ap)[2]; f3 = ((const float4*)ap)[3];
          } else if (k0 < 320) {
            const float* ap = etim + (size_t)htim[base] * 64 + (k0 - 256) + (shalf << 4);
            f0 = ((const float4*)ap)[0]; f1 = ((const float4*)ap)[1];
            f2 = ((const float4*)ap)[2]; f3 = ((const float4*)ap)[3];
          } else {
            const int cu = (k0 - 320) + (shalf << 4);
            const float4* u0 = (const float4*)(euid + (size_t)huid[base + 0] * 128 + cu);
            const float4* u1 = (const float4*)(euid + (size_t)huid[base + 1] * 128 + cu);
            const float4* u2 = (const float4*)(euid + (size_t)huid[base + 2] * 128 + cu);
            const float4* u3 = (const float4*)(euid + (size_t)huid[base + 3] * 128 + cu);
#define AVG4(idx, dst) { float4 a=u0[idx],b4=u1[idx],c4=u2[idx],d4=u3[idx];            \
            dst.x=0.25f*(a.x+b4.x+c4.x+d4.x); dst.y=0.25f*(a.y+b4.y+c4.y+d4.y);       \
            dst.z=0.25f*(a.z+b4.z+c4.z+d4.z); dst.w=0.25f*(a.w+b4.w+c4.w+d4.w); }
            AVG4(0, f0) AVG4(1, f1) AVG4(2, f2) AVG4(3, f3)
#undef AVG4
          }
          short* arow = Asl + srow * LDR + (shalf << 4);
          *(bf16x8*)(arow)     = pack8(f0, f1);
          *(bf16x8*)(arow + 8) = pack8(f2, f3);
          const float* bp = W_attn + (size_t)(bn + srow) * K + k0 + (shalf << 4);
          f0 = ((const float4*)bp)[0]; f1 = ((const float4*)bp)[1];
          f2 = ((const float4*)bp)[2]; f3 = ((const float4*)bp)[3];
          short* brow = Bsl + srow * LDR + (shalf << 4);
          *(bf16x8*)(brow)     = pack8(f0, f1);
          *(bf16x8*)(brow + 8) = pack8(f2, f3);
        }
        __syncthreads();
        bf16x8 af[4], bfr[4];
#pragma unroll
        for (int i = 0; i < 4; ++i) {
          af[i]  = *(const bf16x8*)(Asl + ((wr << 6) + (i << 4) + m16) * LDR + (g4 << 3));
          bfr[i] = *(const bf16x8*)(Bsl + ((wc << 6) + (i << 4) + m16) * LDR + (g4 << 3));
        }
#pragma unroll
        for (int i = 0; i < 4; ++i)
#pragma unroll
          for (int j = 0; j < 4; ++j)
            acc[i][j] = __builtin_amdgcn_mfma_f32_16x16x32_bf16(af[i], bfr[j], acc[i][j], 0, 0, 0);
        __syncthreads();
      }
#pragma unroll
      for (int i = 0; i < 4; ++i)
#pragma unroll
        for (int j = 0; j < 4; ++j) {
          const int col = bn + (wc << 6) + (j << 4) + m16;
          const float bv = b_attn[col];
#pragma unroll
          for (int q = 0; q < 4; ++q) {
            const int row = bm + (wr << 6) + (i << 4) + (g4 << 2) + q;
            histt[(size_t)row * N + col] = tanhf(acc[i][j][q] + bv);
          }
        }
    }
    asm volatile("s_waitcnt vmcnt(0)" ::: "memory");
    if (tid == 0)
      __hip_atomic_fetch_add(flags + 2048, 1u, __ATOMIC_RELEASE, __HIP_MEMORY_SCOPE_AGENT);

    // ---- W_final fold (consumed by NEXT launch; kernel-end flush suffices) ----
    for (int u = bid - 64; u < 5000; u += 128) {
      const int cc = tid << 1;
      float2 a = *(const float2*)(Wf + (size_t)u * 1536 + cc);
      float2 b2 = *(const float2*)(Wf + (size_t)u * 1536 + 1024 + cc);
      float2 o; o.x = a.x + b2.x; o.y = a.y + b2.y;
      *(float2*)(Wfold + (size_t)u * 512 + cc) = o;
    }
  }

  // ===================== fused attn_ctx role (bid 64..127), per-batch gated =====================
  if (bid < 128) {
    const int b = bid - 64;
    if (tid == 0) {                      // single guarded poller
      while (__hip_atomic_load(flags + 2048, __ATOMIC_RELAXED, __HIP_MEMORY_SCOPE_AGENT) < 128u)
        __builtin_amdgcn_s_sleep(7);
      while (__hip_atomic_load(flags + 1024 + (b << 4), __ATOMIC_RELAXED, __HIP_MEMORY_SCOPE_AGENT) < 16u)
        __builtin_amdgcn_s_sleep(7);
    }
    __syncthreads();
    __builtin_amdgcn_fence(__ATOMIC_ACQUIRE, "agent");
    float* ls  = (float*)smem;
    float* wv  = ls + 512;
    float* red = wv + 256;
    ((float2*)ls)[tid] = ((const float2*)(lastb + (size_t)b * 512))[tid];
    __syncthreads();
    const float* hb = histt + (size_t)b * 256 * 512;
    const float* hrow = hb + (size_t)tid * 512;
    float acc = 0.f;
    for (int k = 0; k < 512; k += 4) {
      float4 h4 = *(const float4*)(hrow + k);
      acc += ls[k] * h4.x + ls[k + 1] * h4.y + ls[k + 2] * h4.z + ls[k + 3] * h4.w;
    }
    red[tid] = acc;
    __syncthreads();
    for (int s = 128; s; s >>= 1) {
      if (tid < s) red[tid] = fmaxf(red[tid], red[tid + s]);
      __syncthreads();
    }
    float m = red[0];
    __syncthreads();
    float ex = expf(acc - m);
    wv[tid] = ex; red[tid] = ex;
    __syncthreads();
    for (int s = 128; s; s >>= 1) {
      if (tid < s) red[tid] += red[tid + s];
      __syncthreads();
    }
    float inv = 1.f / red[0];
    float c0 = 0.f, c1 = 0.f;
    for (int n = 0; n < 256; ++n) {
      float wn = wv[n];
      c0 += wn * hb[(size_t)n * 512 + tid];
      c1 += wn * hb[(size_t)n * 512 + tid + 256];
    }
    ctx[(size_t)b * 512 + tid]       = c0 * inv;
    ctx[(size_t)b * 512 + tid + 256] = c1 * inv;
  }
}

// ---------------- final (K=1024): y[b][u] = last.Wfold[u] + ctx.Wf[u,512:1024] + bf[u] ----------------
__global__ __launch_bounds__(256)
void final_gemm(const float* __restrict__ last, const float* __restrict__ ctx,
                const float* __restrict__ Wfold, const float* __restrict__ Wf,
                const float* __restrict__ bf, float* __restrict__ y) {
  __shared__ float s[64][132];
  const int tid = threadIdx.x;
  const int u0 = blockIdx.x << 3;
  const int ul = tid >> 6, b = tid & 63;
  float acc0 = 0.f, acc1 = 0.f;
  for (int kc = 0; kc < 8; ++kc) {
    __syncthreads();
    for (int i = tid; i < 2048; i += 256) {
      int rb = i >> 5, cc = (i & 31) << 2;
      int k = kc * 128 + cc;
      const float* src = (k < 512) ? (last + (size_t)rb * 512 + k)
                                   : (ctx + (size_t)rb * 512 + k - 512);
      *(float4*)&s[rb][cc] = *(const float4*)src;
    }
    __syncthreads();
#pragma unroll
    for (int uu = 0; uu < 2; ++uu) {
      int u = u0 + ul + uu * 4;
      const float* wrow = (kc < 4) ? (Wfold + (size_t)u * 512 + kc * 128)
                                   : (Wf + (size_t)u * 1536 + 512 + (kc - 4) * 128);
      float a = 0.f;
#pragma unroll 8
      for (int c = 0; c < 128; c += 4) {
        float4 w4 = *(const float4*)(wrow + c);
        float4 s4 = *(const float4*)&s[b][c];
        a += w4.x * s4.x + w4.y * s4.y + w4.z * s4.z + w4.w * s4.w;
      }
      if (uu == 0) acc0 += a; else acc1 += a;
    }
  }
  int u = u0 + ul;
  y[(size_t)b * 5000 + u]     = acc0 + bf[u];
  y[(size_t)b * 5000 + u + 4] = acc1 + bf[u + 4];
}

// ---------------- broadcast y (B,5000) -> out (B,T,5000) ----------------
__global__ void broadcast_y(const float* __restrict__ y, float* __restrict__ out) {
  int bt = blockIdx.x;
  const float4* src = (const float4*)(y + (size_t)(bt >> 7) * 5000);
  float4* dst = (float4*)(out + (size_t)bt * 5000);
  for (int i = threadIdx.x; i < 1250; i += 256) dst[i] = src[i];
}

extern "C" void kernel_launch(void* const* d_in, const int* in_sizes, int n_in,
                              void* d_out, int out_size, void* d_ws, size_t ws_size,
                              hipStream_t stream) {
  const int* loc  = (const int*)d_in[0];
  const int* tim  = (const int*)d_in[1];
  const int* lens = (const int*)d_in[2];
  const int* hloc = (const int*)d_in[3];
  const int* htim = (const int*)d_in[4];
  const int* huid = (const int*)d_in[5];
  // d_in[6] = group_size (constant 4, baked in)
  const float* eloc    = (const float*)d_in[7];
  const float* etim    = (const float*)d_in[8];
  const float* euid    = (const float*)d_in[9];
  const float* W_attn  = (const float*)d_in[10];
  const float* b_attn  = (const float*)d_in[11];
  const float* W_ih    = (const float*)d_in[12];
  const float* b_ih    = (const float*)d_in[13];
  const float* W_hh    = (const float*)d_in[14];
  const float* b_hh    = (const float*)d_in[15];
  const float* W_final = (const float*)d_in[16];
  const float* b_final = (const float*)d_in[17];
  float* out = (float*)d_out;
  char* ws = (char*)d_ws;

  // workspace layout (bytes)
  short* gxb   = (short*)(ws + 0ull);            // 8192*1536*2 = 25,165,824
  float* histt = (float*)(ws + 25165824ull);     // 16384*512*4 = 33,554,432
  float* lastb = (float*)(ws + 58720256ull);     // 64*512*4 = 131,072
  float* ctx   = (float*)(ws + 58851328ull);     // 131,072
  float* yv    = (float*)(ws + 58982400ull);     // 64*5000*4 = 1,280,000
  short* h_bf  = (short*)(ws + 60262400ull);     // 2*64*512*2 = 131,072
  unsigned int* flags = (unsigned int*)(ws + 60393472ull);   // 16 KB
  float* Wfold = (float*)(ws + 60409856ull);     // 5000*512*4 = 10,240,000 (end ~70.6 MB)

  hipMemsetAsync(flags, 0, 16384, stream);       // before gemm: off the critical path
  gemm_gx_f<<<dim3(12, 64), 256, 0, stream>>>(loc, tim, eloc, etim, W_ih, b_ih, gxb);

  gru_attn<<<192, 256, 0, stream>>>(gxb, W_hh, b_hh, lens, h_bf, lastb, flags,
                                    hloc, htim, huid, eloc, etim, euid,
                                    W_attn, b_attn, W_final, Wfold, histt, ctx);

  final_gemm<<<625, 256, 0, stream>>>(lastb, ctx, Wfold, W_final, b_final, yv);
  broadcast_y<<<8192, 256, 0, stream>>>(yv, out);
}